// Round 13
// baseline (69.995 us; speedup 1.0000x reference)
//
#include <hip/hip_runtime.h>
#include <stdint.h>

#define N_ 2048
#define D_ 128
#define B_ 8
#define NT 16            // N_/128
#define NPAIRS 136       // NT*(NT+1)/2
#define NBINS 8192
#define GH 17            // hist block-groups per pair
#define TPG 8            // tiles per hist block (GH*TPG == NPAIRS)

typedef __attribute__((ext_vector_type(8))) _Float16 half8;
typedef __attribute__((ext_vector_type(4))) float f32x4;

// ws layout (bytes)
#define OFF_ACCUM 0
#define OFF_DONE  64
#define OFF_RU    256                               // 16 int entries, 64B stride
#define OFF_THR   1280                              // 16 floats
#define OFF_REP   4096                              // 16*17*16384 = 4.46 MB
#define OFF_F     (OFF_REP + (size_t)16*GH*(NBINS*2))
#define NEED      (OFF_F + (size_t)16*N_*D_*2)

// Fragment-major f16 panel: panel p (2048 rows x 128 k) as [128 rt][4 kt]
// 1KB fragments; within a fragment lane l=(r&15)+((k>>3)&3)*16 owns 16B at l*16.

// Eighth tile: fragment-row mm=0, fragment-cols nn<2 per wave ->
// rows (r mod 64)<16, cols (c mod 64)<32. 8 MFMA instead of 64. Hist sampling.
__device__ __forceinline__ void gemm16_e(const _Float16* __restrict__ Fp,
        int ti, int tj, f32x4 acc[2], int t)
{
    const int lane = t & 63;
    const int wv = t >> 6, wr = wv >> 1, wc = wv & 1;
    const _Float16* A  = Fp + (size_t)(ti*8 + wr*4)*2048 + (size_t)lane*8;
    const _Float16* Bp = Fp + (size_t)(tj*8 + wc*4)*2048 + (size_t)lane*8;

    half8 a[2], b[2][2];
    a[0] = *(const half8*)&A[0];
    #pragma unroll
    for (int nn = 0; nn < 2; ++nn) b[0][nn] = *(const half8*)&Bp[nn*2048];
    #pragma unroll
    for (int nn = 0; nn < 2; ++nn) acc[nn] = f32x4{0.f, 0.f, 0.f, 0.f};

    #pragma unroll
    for (int kt = 0; kt < 4; ++kt) {
        const int cur = kt & 1, nxt = cur ^ 1;
        if (kt < 3) {
            a[nxt] = *(const half8*)&A[(kt+1)*512];
            #pragma unroll
            for (int nn = 0; nn < 2; ++nn)
                b[nxt][nn] = *(const half8*)&Bp[nn*2048 + (kt+1)*512];
        }
        #pragma unroll
        for (int nn = 0; nn < 2; ++nn)
            acc[nn] = __builtin_amdgcn_mfma_f32_16x16x32_f16(a[cur], b[cur][nn], acc[nn], 0, 0, 0);
    }
}

// f32 -> f16 fragment-major panels + fused per-pair max row-norm^2.
// Ru is int float-bits via atomicMax(int): positive floats compare as ints,
// and leftover/poison values are negative or idempotent -> no pre-zero needed.
__global__ __launch_bounds__(256) void convert_kernel(
    const float* __restrict__ Xin, const float* __restrict__ Xtg,
    _Float16* __restrict__ F, int* __restrict__ Ru)
{
    const int t = threadIdx.x;
    const int m = blockIdx.y;
    const float* X = m ? Xtg : Xin;
    const size_t e8 = (size_t)blockIdx.x * 256 + t;
    const size_t idx = e8 * 8;
    const int b = (int)(e8 >> 15);
    const int r = (int)((idx >> 7) & 2047);
    const int k = (int)(idx & 127);

    float4 v0 = *(const float4*)&X[idx];
    float4 v1 = *(const float4*)&X[idx + 4];
    float vv[8] = {v0.x, v0.y, v0.z, v0.w, v1.x, v1.y, v1.z, v1.w};
    _Float16 h8[8];
    float s = 0.f;
    #pragma unroll
    for (int j = 0; j < 8; ++j) {
        float f = fminf(fmaxf(vv[j], -60000.f), 60000.f);  // f16-range guard
        h8[j] = (_Float16)f;
        s += vv[j] * vv[j];
    }
    const int p = m * B_ + b;
    const size_t off = (size_t)p * (N_*D_)
        + (size_t)((r >> 4) * 4 + (k >> 5)) * 512
        + (size_t)((r & 15) + ((k >> 3) & 3) * 16) * 8;
    *(half8*)&F[off] = *(half8*)h8;

    // 16 consecutive lanes cover one row of 128 k
    s += __shfl_xor(s, 1); s += __shfl_xor(s, 2); s += __shfl_xor(s, 4); s += __shfl_xor(s, 8);
    s = fmaxf(s, __shfl_xor(s, 16)); s = fmaxf(s, __shfl_xor(s, 32));
    __shared__ float wm[4];
    if ((t & 63) == 0) wm[t >> 6] = s;
    __syncthreads();
    if (t == 0) {
        float mx = fmaxf(fmaxf(wm[0], wm[1]), fmaxf(wm[2], wm[3]));
        atomicMax(&Ru[p * 16], __float_as_int(mx));   // positive: int order == float order
    }
}

// Sampled (1/8) 8K-bin hist of POSITIVE sims over (0,R]: eighth-tile GEMM.
// Packed-u16 LDS, non-atomic replica flush. v<=0 skipped.
// Low 4 bits of blockIdx carry p -> pair pinned to one XCD L2.
__global__ __launch_bounds__(256) void hist_kernel(
    const _Float16* __restrict__ F, const int* __restrict__ Ru,
    uint32_t* __restrict__ rep)
{
    __shared__ uint32_t lh[NBINS / 2];   // 16 KB packed u16 pairs
    const int t = threadIdx.x;
    const int id = blockIdx.x;
    const int p = id & 15, g = id >> 4;

    for (int i = t; i < NBINS/2; i += 256) lh[i] = 0;
    __syncthreads();

    const _Float16* Fp = F + (size_t)p * (N_*D_);
    const float R = __int_as_float(Ru[p * 16]);
    const float scl = (float)NBINS / R;

    for (int j = 0; j < TPG; ++j) {
        int rem = g * TPG + j, ti = 0;
        while (true) { int len = NT - ti; if (rem < len) break; rem -= len; ++ti; }
        const int tj = ti + rem;
        const uint32_t w = (ti == tj) ? 1u : 2u;

        f32x4 acc[2];
        gemm16_e(Fp, ti, tj, acc, t);
        #pragma unroll
        for (int nn = 0; nn < 2; ++nn)
            #pragma unroll
            for (int r = 0; r < 4; ++r) {
                float v = acc[nn][r];
                if (v > 0.f) {
                    int bin = (int)(v * scl);
                    if (bin >= NBINS) bin = NBINS - 1;
                    atomicAdd(&lh[bin >> 1], w << ((bin & 1) * 16));
                }
            }
    }
    __syncthreads();
    uint32_t* dst = rep + ((size_t)p * GH + g) * (NBINS/2);
    for (int i = t; i < NBINS/2; i += 256) dst[i] = lh[i];
}

// Fused: sum GH replicas into LDS u32 hist (1024 threads, coalesced) ->
// descending scan -> thr[p]. Block 0 also zeroes accum/done for mse.
__global__ __launch_bounds__(1024) void reduce_select(
    const uint32_t* __restrict__ rep, const int* __restrict__ kptr,
    const int* __restrict__ Ru, float* __restrict__ thr,
    double* __restrict__ accum, uint32_t* __restrict__ done)
{
    __shared__ uint32_t h[NBINS];        // 32 KB
    __shared__ uint32_t csum[256], cpre[256];
    const int p = blockIdx.x, t = threadIdx.x;
    if (p == 0 && t == 0) { accum[0] = 0.0; done[0] = 0u; }

    const uint32_t* base = rep + (size_t)p * GH * (NBINS/2);
    #pragma unroll
    for (int j = 0; j < NBINS/2/1024; ++j) {   // 4096 words / 1024 threads = 4
        const int wd = j * 1024 + t;
        uint32_t lo = 0, hi = 0;
        #pragma unroll
        for (int g = 0; g < GH; ++g) {
            uint32_t x = base[(size_t)g * (NBINS/2) + wd];
            lo += x & 0xffffu; hi += x >> 16;
        }
        h[wd*2] = lo; h[wd*2 + 1] = hi;
    }
    __syncthreads();

    const uint32_t k0 = ((uint32_t)kptr[0] + 4u) >> 3;   // sampled rank (1/8)
    const float R = __int_as_float(Ru[p * 16]);
    const float binw = R / (float)NBINS;

    if (t < 256) {
        const int top = NBINS - 1 - t * 32;
        uint32_t s = 0;
        #pragma unroll
        for (int j = 0; j < 32; ++j) s += h[top - j];
        csum[t] = s;
    }
    __syncthreads();
    if (t == 0) { uint32_t run = 0; for (int i = 0; i < 256; ++i) { cpre[i] = run; run += csum[i]; } }
    __syncthreads();
    if (t < 256) {
        const uint32_t above = cpre[t];
        const uint32_t s = csum[t];
        if (above < k0 && above + s >= k0) {
            uint32_t cum = above;
            const int top = NBINS - 1 - t * 32;
            for (int j = 0; j < 32; ++j) {
                int bin = top - j;
                cum += h[bin];
                if (cum >= k0) { thr[p] = (float)bin * binw; break; }   // lower edge
            }
        }
    }
}

// masked MSE: merged dual-side GEMM pipeline (R11 config: 256 thr, 64x64/wave,
// 8 unrolled steps, shared operand double-buffer, dual accumulators).
// Last-block pattern folds the finalize: done counter + threadfence.
// Low 3 bits of blockIdx carry p -> both panels (2MB) on one XCD L2.
__global__ __launch_bounds__(256) void mse_kernel(
    const _Float16* __restrict__ F, const float* __restrict__ thr,
    double* __restrict__ accum, uint32_t* __restrict__ done,
    float* __restrict__ out)
{
    const int t = threadIdx.x;
    const int id = blockIdx.x;
    const int p = id & 7, tile = id >> 3;

    int rem = tile, ti = 0;
    while (true) { int len = NT - ti; if (rem < len) break; rem -= len; ++ti; }
    const int tj = ti + rem;
    const uint32_t w = (ti == tj) ? 1u : 2u;

    const int lane = t & 63;
    const int wv = t >> 6, wr = wv >> 1, wc = wv & 1;
    const _Float16* FI = F + (size_t)p * (N_*D_);
    const _Float16* FT = F + (size_t)(B_ + p) * (N_*D_);
    const _Float16* AI = FI + (size_t)(ti*8 + wr*4)*2048 + (size_t)lane*8;
    const _Float16* BI = FI + (size_t)(tj*8 + wc*4)*2048 + (size_t)lane*8;
    const _Float16* AT = FT + (size_t)(ti*8 + wr*4)*2048 + (size_t)lane*8;
    const _Float16* BT = FT + (size_t)(tj*8 + wc*4)*2048 + (size_t)lane*8;

    f32x4 accI[4][4], accT[4][4];
    #pragma unroll
    for (int mm = 0; mm < 4; ++mm)
        #pragma unroll
        for (int nn = 0; nn < 4; ++nn) {
            accI[mm][nn] = f32x4{0.f, 0.f, 0.f, 0.f};
            accT[mm][nn] = f32x4{0.f, 0.f, 0.f, 0.f};
        }

    half8 a[2][4], b[2][4];
    #pragma unroll
    for (int mm = 0; mm < 4; ++mm) {
        a[0][mm] = *(const half8*)&AI[mm*2048];
        b[0][mm] = *(const half8*)&BI[mm*2048];
    }

    #pragma unroll
    for (int s = 0; s < 8; ++s) {
        const int cur = s & 1, nxt = cur ^ 1;
        if (s < 7) {
            const int s2 = s + 1, kt2 = s2 & 3;
            const _Float16* A2 = (s2 < 4) ? AI : AT;
            const _Float16* B2 = (s2 < 4) ? BI : BT;
            #pragma unroll
            for (int mm = 0; mm < 4; ++mm) {
                a[nxt][mm] = *(const half8*)&A2[mm*2048 + kt2*512];
                b[nxt][mm] = *(const half8*)&B2[mm*2048 + kt2*512];
            }
        }
        if (s < 4) {
            #pragma unroll
            for (int mm = 0; mm < 4; ++mm)
                #pragma unroll
                for (int nn = 0; nn < 4; ++nn)
                    accI[mm][nn] = __builtin_amdgcn_mfma_f32_16x16x32_f16(a[cur][mm], b[cur][nn], accI[mm][nn], 0, 0, 0);
        } else {
            #pragma unroll
            for (int mm = 0; mm < 4; ++mm)
                #pragma unroll
                for (int nn = 0; nn < 4; ++nn)
                    accT[mm][nn] = __builtin_amdgcn_mfma_f32_16x16x32_f16(a[cur][mm], b[cur][nn], accT[mm][nn], 0, 0, 0);
        }
    }

    const float thrI = thr[p], thrT = thr[B_ + p];
    float local = 0.f;
    #pragma unroll
    for (int mm = 0; mm < 4; ++mm)
        #pragma unroll
        for (int nn = 0; nn < 4; ++nn)
            #pragma unroll
            for (int r = 0; r < 4; ++r) {
                float vI = accI[mm][nn][r], aI = (vI >= thrI) ? vI : 0.f;
                float vT = accT[mm][nn][r], aT = (vT >= thrT) ? vT : 0.f;
                float d = aI - aT;
                local += d * d;
            }
    local *= (float)w;
    #pragma unroll
    for (int off = 32; off; off >>= 1) local += __shfl_down(local, off);
    __shared__ float wsum[4];
    if ((t & 63) == 0) wsum[t >> 6] = local;
    __syncthreads();
    if (t == 0) {
        double s2 = (double)wsum[0] + (double)wsum[1] + (double)wsum[2] + (double)wsum[3];
        atomicAdd(accum, s2);
        __threadfence();
        uint32_t prev = atomicAdd(done, 1u);
        if (prev == (uint32_t)(NPAIRS * 8 - 1)) {
            double total = atomicAdd(accum, 0.0);   // atomic read, all adds visible
            out[0] = (float)(total / ((double)B_ * (double)N_ * (double)N_));
        }
    }
}

extern "C" void kernel_launch(void* const* d_in, const int* in_sizes, int n_in,
                              void* d_out, int out_size, void* d_ws, size_t ws_size,
                              hipStream_t stream)
{
    const float* Xin = (const float*)d_in[0];
    const float* Xtg = (const float*)d_in[1];
    const int*  kptr = (const int*)d_in[3];
    float* out = (float*)d_out;

    char* ws = (char*)d_ws;
    double*    accum = (double*)   (ws + OFF_ACCUM);
    uint32_t*  done  = (uint32_t*) (ws + OFF_DONE);
    int*       Ru    = (int*)      (ws + OFF_RU);
    float*     thr   = (float*)    (ws + OFF_THR);
    uint32_t*  rep   = (uint32_t*) (ws + OFF_REP);
    _Float16*  F     = (_Float16*) (ws + OFF_F);
    if (ws_size < NEED) return;

    dim3 blk(256);
    convert_kernel<<<dim3(1024, 2), blk, 0, stream>>>(Xin, Xtg, F, Ru);
    hist_kernel<<<dim3(GH * 16), blk, 0, stream>>>(F, Ru, rep);
    reduce_select<<<dim3(16), dim3(1024), 0, stream>>>(rep, kptr, Ru, thr, accum, done);
    mse_kernel<<<dim3(NPAIRS * 8), blk, 0, stream>>>(F, thr, accum, done, out);
}

// Round 14
// 69.881 us; speedup vs baseline: 1.0016x; 1.0016x over previous
//
#include <hip/hip_runtime.h>
#include <stdint.h>

#define N_ 2048
#define D_ 128
#define B_ 8
#define NT 16            // N_/128
#define NPAIRS 136       // NT*(NT+1)/2
#define NBINS 8192
#define GH 17            // hist block-groups per pair
#define TPG 8            // tiles per hist block (GH*TPG == NPAIRS)

typedef __attribute__((ext_vector_type(8))) _Float16 half8;
typedef __attribute__((ext_vector_type(4))) float f32x4;

// ws layout (bytes)
#define OFF_ACCUM 0
#define OFF_DONE  64
#define OFF_RU    256                               // 16 int entries, 64B stride
#define OFF_THR   1280                              // 16 floats
#define OFF_H32   4096                              // 16*8192*4 = 512 KB
#define OFF_REP   (4096 + (size_t)16*NBINS*4)       // 16*17*16384 = 4.46 MB
#define OFF_F     (OFF_REP + (size_t)16*GH*(NBINS*2))
#define NEED      (OFF_F + (size_t)16*N_*D_*2)

// Fragment-major f16 panel: panel p (2048 rows x 128 k) as [128 rt][4 kt]
// 1KB fragments; within a fragment lane l=(r&15)+((k>>3)&3)*16 owns 16B at l*16.

// Eighth tile: fragment-row mm=0, fragment-cols nn<2 per wave ->
// rows (r mod 64)<16, cols (c mod 64)<32. 8 MFMA instead of 64. Hist sampling.
__device__ __forceinline__ void gemm16_e(const _Float16* __restrict__ Fp,
        int ti, int tj, f32x4 acc[2], int t)
{
    const int lane = t & 63;
    const int wv = t >> 6, wr = wv >> 1, wc = wv & 1;
    const _Float16* A  = Fp + (size_t)(ti*8 + wr*4)*2048 + (size_t)lane*8;
    const _Float16* Bp = Fp + (size_t)(tj*8 + wc*4)*2048 + (size_t)lane*8;

    half8 a[2], b[2][2];
    a[0] = *(const half8*)&A[0];
    #pragma unroll
    for (int nn = 0; nn < 2; ++nn) b[0][nn] = *(const half8*)&Bp[nn*2048];
    #pragma unroll
    for (int nn = 0; nn < 2; ++nn) acc[nn] = f32x4{0.f, 0.f, 0.f, 0.f};

    #pragma unroll
    for (int kt = 0; kt < 4; ++kt) {
        const int cur = kt & 1, nxt = cur ^ 1;
        if (kt < 3) {
            a[nxt] = *(const half8*)&A[(kt+1)*512];
            #pragma unroll
            for (int nn = 0; nn < 2; ++nn)
                b[nxt][nn] = *(const half8*)&Bp[nn*2048 + (kt+1)*512];
        }
        #pragma unroll
        for (int nn = 0; nn < 2; ++nn)
            acc[nn] = __builtin_amdgcn_mfma_f32_16x16x32_f16(a[cur], b[cur][nn], acc[nn], 0, 0, 0);
    }
}

// f32 -> f16 fragment-major panels + fused per-pair max row-norm^2.
// Ru is int float-bits via atomicMax(int): positive floats compare as ints;
// poison (0xAA..) is negative -> never wins; re-runs idempotent. No pre-zero.
__global__ __launch_bounds__(256) void convert_kernel(
    const float* __restrict__ Xin, const float* __restrict__ Xtg,
    _Float16* __restrict__ F, int* __restrict__ Ru)
{
    const int t = threadIdx.x;
    const int m = blockIdx.y;
    const float* X = m ? Xtg : Xin;
    const size_t e8 = (size_t)blockIdx.x * 256 + t;
    const size_t idx = e8 * 8;
    const int b = (int)(e8 >> 15);
    const int r = (int)((idx >> 7) & 2047);
    const int k = (int)(idx & 127);

    float4 v0 = *(const float4*)&X[idx];
    float4 v1 = *(const float4*)&X[idx + 4];
    float vv[8] = {v0.x, v0.y, v0.z, v0.w, v1.x, v1.y, v1.z, v1.w};
    _Float16 h8[8];
    float s = 0.f;
    #pragma unroll
    for (int j = 0; j < 8; ++j) {
        float f = fminf(fmaxf(vv[j], -60000.f), 60000.f);  // f16-range guard
        h8[j] = (_Float16)f;
        s += vv[j] * vv[j];
    }
    const int p = m * B_ + b;
    const size_t off = (size_t)p * (N_*D_)
        + (size_t)((r >> 4) * 4 + (k >> 5)) * 512
        + (size_t)((r & 15) + ((k >> 3) & 3) * 16) * 8;
    *(half8*)&F[off] = *(half8*)h8;

    // 16 consecutive lanes cover one row of 128 k
    s += __shfl_xor(s, 1); s += __shfl_xor(s, 2); s += __shfl_xor(s, 4); s += __shfl_xor(s, 8);
    s = fmaxf(s, __shfl_xor(s, 16)); s = fmaxf(s, __shfl_xor(s, 32));
    __shared__ float wm[4];
    if ((t & 63) == 0) wm[t >> 6] = s;
    __syncthreads();
    if (t == 0) {
        float mx = fmaxf(fmaxf(wm[0], wm[1]), fmaxf(wm[2], wm[3]));
        atomicMax(&Ru[p * 16], __float_as_int(mx));   // positive: int order == float order
    }
}

// Sampled (1/8) 8K-bin hist of POSITIVE sims over (0,R]: eighth-tile GEMM.
// Packed-u16 LDS, non-atomic replica flush. v<=0 skipped.
// Low 4 bits of blockIdx carry p -> pair pinned to one XCD L2.
__global__ __launch_bounds__(256) void hist_kernel(
    const _Float16* __restrict__ F, const int* __restrict__ Ru,
    uint32_t* __restrict__ rep)
{
    __shared__ uint32_t lh[NBINS / 2];   // 16 KB packed u16 pairs
    const int t = threadIdx.x;
    const int id = blockIdx.x;
    const int p = id & 15, g = id >> 4;

    for (int i = t; i < NBINS/2; i += 256) lh[i] = 0;
    __syncthreads();

    const _Float16* Fp = F + (size_t)p * (N_*D_);
    const float R = __int_as_float(Ru[p * 16]);
    const float scl = (float)NBINS / R;

    for (int j = 0; j < TPG; ++j) {
        int rem = g * TPG + j, ti = 0;
        while (true) { int len = NT - ti; if (rem < len) break; rem -= len; ++ti; }
        const int tj = ti + rem;
        const uint32_t w = (ti == tj) ? 1u : 2u;

        f32x4 acc[2];
        gemm16_e(Fp, ti, tj, acc, t);
        #pragma unroll
        for (int nn = 0; nn < 2; ++nn)
            #pragma unroll
            for (int r = 0; r < 4; ++r) {
                float v = acc[nn][r];
                if (v > 0.f) {
                    int bin = (int)(v * scl);
                    if (bin >= NBINS) bin = NBINS - 1;
                    atomicAdd(&lh[bin >> 1], w << ((bin & 1) * 16));
                }
            }
    }
    __syncthreads();
    uint32_t* dst = rep + ((size_t)p * GH + g) * (NBINS/2);
    for (int i = t; i < NBINS/2; i += 256) dst[i] = lh[i];
}

// parallel replica reduce: 256 blocks (16 pairs x 16 chunks), coalesced.
__global__ __launch_bounds__(256) void reduce_kernel(
    const uint32_t* __restrict__ rep, uint32_t* __restrict__ h32)
{
    const int id = blockIdx.x;
    const int p = id & 15, chunk = id >> 4;
    const int t = threadIdx.x;
    const int wd = chunk * 256 + t;                 // packed-word idx 0..4095
    const uint32_t* base = rep + (size_t)p * GH * (NBINS/2) + wd;
    uint32_t lo = 0, hi = 0;
    #pragma unroll
    for (int g = 0; g < GH; ++g) {
        uint32_t x = base[(size_t)g * (NBINS/2)];
        lo += x & 0xffffu; hi += x >> 16;
    }
    uint32_t* hp = h32 + (size_t)p * NBINS;
    hp[wd*2]     = lo;
    hp[wd*2 + 1] = hi;
}

// descending scan of u32 hist, rank k/8 (1/8 sample): thr = bin lower edge.
// Block 0 also zeroes accum/done for mse (runs before mse in stream order).
__global__ __launch_bounds__(256) void select_kernel(
    const uint32_t* __restrict__ h32, const int* __restrict__ kptr,
    const int* __restrict__ Ru, float* __restrict__ thr,
    double* __restrict__ accum, uint32_t* __restrict__ done)
{
    __shared__ uint32_t csum[256], cpre[256];
    const int p = blockIdx.x, t = threadIdx.x;
    if (p == 0 && t == 0) { accum[0] = 0.0; done[0] = 0u; }
    const uint32_t* h = h32 + (size_t)p * NBINS;
    const uint32_t k0 = ((uint32_t)kptr[0] + 4u) >> 3;   // sampled rank
    const float R = __int_as_float(Ru[p * 16]);
    const float binw = R / (float)NBINS;

    const int top = NBINS - 1 - t * 32;
    uint32_t s = 0;
    #pragma unroll
    for (int j = 0; j < 32; ++j) s += h[top - j];
    csum[t] = s;
    __syncthreads();
    if (t == 0) { uint32_t run = 0; for (int i = 0; i < 256; ++i) { cpre[i] = run; run += csum[i]; } }
    __syncthreads();
    const uint32_t above = cpre[t];
    if (above < k0 && above + s >= k0) {
        uint32_t cum = above;
        for (int j = 0; j < 32; ++j) {
            int bin = top - j;
            cum += h[bin];
            if (cum >= k0) { thr[p] = (float)bin * binw; break; }   // lower edge
        }
    }
}

// masked MSE: 512 threads, 8 waves. Waves 0-3 compute input-side sim (64x64
// quadrants), waves 4-7 target-side. Each side masks with its threshold and
// writes f16 values to a 64KB LDS exchange (flat packing, identical bijection
// both sides -> layout-agnostic); then all waves diff-square-reduce.
// Per-wave regs ~148 -> 3 waves/SIMD (vs 2 for the fused dual-acc version).
// Low 3 bits of blockIdx carry p -> both panels (2MB) on one XCD L2.
__global__ __launch_bounds__(512, 3) void mse_kernel(
    const _Float16* __restrict__ F, const float* __restrict__ thr,
    double* __restrict__ accum, uint32_t* __restrict__ done,
    float* __restrict__ out)
{
    __shared__ _Float16 lbuf[2][16384];   // [side][128x128] flat-packed, 64 KB
    __shared__ float wsum[8];

    const int t = threadIdx.x;
    const int id = blockIdx.x;
    const int p = id & 7, tile = id >> 3;

    int rem = tile, ti = 0;
    while (true) { int len = NT - ti; if (rem < len) break; rem -= len; ++ti; }
    const int tj = ti + rem;
    const uint32_t w = (ti == tj) ? 1u : 2u;

    const int lane = t & 63;
    const int wv = t >> 6;
    const int side = wv >> 2;             // 0 = input, 1 = target
    const int quad = wv & 3, wr = quad >> 1, wc = quad & 1;

    const _Float16* Fp = F + (size_t)(side ? B_ + p : p) * (N_*D_);
    const _Float16* A  = Fp + (size_t)(ti*8 + wr*4)*2048 + (size_t)lane*8;
    const _Float16* Bp = Fp + (size_t)(tj*8 + wc*4)*2048 + (size_t)lane*8;

    f32x4 acc[4][4];
    #pragma unroll
    for (int mm = 0; mm < 4; ++mm)
        #pragma unroll
        for (int nn = 0; nn < 4; ++nn)
            acc[mm][nn] = f32x4{0.f, 0.f, 0.f, 0.f};

    half8 a[2][4], b[2][4];
    #pragma unroll
    for (int mm = 0; mm < 4; ++mm) {
        a[0][mm] = *(const half8*)&A[mm*2048];
        b[0][mm] = *(const half8*)&Bp[mm*2048];
    }
    #pragma unroll
    for (int kt = 0; kt < 4; ++kt) {
        const int cur = kt & 1, nxt = cur ^ 1;
        if (kt < 3) {
            #pragma unroll
            for (int mm = 0; mm < 4; ++mm) {
                a[nxt][mm] = *(const half8*)&A[mm*2048 + (kt+1)*512];
                b[nxt][mm] = *(const half8*)&Bp[mm*2048 + (kt+1)*512];
            }
        }
        #pragma unroll
        for (int mm = 0; mm < 4; ++mm)
            #pragma unroll
            for (int nn = 0; nn < 4; ++nn)
                acc[mm][nn] = __builtin_amdgcn_mfma_f32_16x16x32_f16(a[cur][mm], b[cur][nn], acc[mm][nn], 0, 0, 0);
    }

    // mask + stage to LDS: per (mm,nn) each lane owns r=0..3 contiguous at
    // half-index quad*4096 + ((mm*4+nn)*64 + lane)*4  -> 8B half4 writes,
    // lanes stride 8B -> 2-way bank aliasing (free).
    const float thrS = thr[side ? B_ + p : p];
    _Float16* Lb = &lbuf[side][quad * 4096];
    #pragma unroll
    for (int mm = 0; mm < 4; ++mm)
        #pragma unroll
        for (int nn = 0; nn < 4; ++nn) {
            _Float16 h4[4];
            #pragma unroll
            for (int r = 0; r < 4; ++r) {
                float v = acc[mm][nn][r];
                h4[r] = (_Float16)((v >= thrS) ? v : 0.f);
            }
            *(ushort4*)&Lb[((mm*4 + nn)*64 + lane)*4] = *(ushort4*)h4;
        }
    __syncthreads();

    // diff phase: thread t handles halves [t*8 + j*4096, +8) of both buffers
    // -> 16B/lane consecutive -> conflict-free b128 reads.
    float local = 0.f;
    #pragma unroll
    for (int j = 0; j < 4; ++j) {
        half8 x = *(const half8*)&lbuf[0][t*8 + j*4096];
        half8 y = *(const half8*)&lbuf[1][t*8 + j*4096];
        #pragma unroll
        for (int e = 0; e < 8; ++e) {
            float d = (float)x[e] - (float)y[e];
            local += d * d;
        }
    }
    local *= (float)w;
    #pragma unroll
    for (int off = 32; off; off >>= 1) local += __shfl_down(local, off);
    if ((t & 63) == 0) wsum[t >> 6] = local;
    __syncthreads();
    if (t == 0) {
        double s2 = 0.0;
        #pragma unroll
        for (int i = 0; i < 8; ++i) s2 += (double)wsum[i];
        atomicAdd(accum, s2);
        __threadfence();
        uint32_t prev = atomicAdd(done, 1u);
        if (prev == (uint32_t)(NPAIRS * 8 - 1)) {
            double total = atomicAdd(accum, 0.0);   // atomic read, all adds visible
            out[0] = (float)(total / ((double)B_ * (double)N_ * (double)N_));
        }
    }
}

extern "C" void kernel_launch(void* const* d_in, const int* in_sizes, int n_in,
                              void* d_out, int out_size, void* d_ws, size_t ws_size,
                              hipStream_t stream)
{
    const float* Xin = (const float*)d_in[0];
    const float* Xtg = (const float*)d_in[1];
    const int*  kptr = (const int*)d_in[3];
    float* out = (float*)d_out;

    char* ws = (char*)d_ws;
    double*    accum = (double*)   (ws + OFF_ACCUM);
    uint32_t*  done  = (uint32_t*) (ws + OFF_DONE);
    int*       Ru    = (int*)      (ws + OFF_RU);
    float*     thr   = (float*)    (ws + OFF_THR);
    uint32_t*  h32   = (uint32_t*) (ws + OFF_H32);
    uint32_t*  rep   = (uint32_t*) (ws + OFF_REP);
    _Float16*  F     = (_Float16*) (ws + OFF_F);
    if (ws_size < NEED) return;

    dim3 blk(256);
    convert_kernel<<<dim3(1024, 2), blk, 0, stream>>>(Xin, Xtg, F, Ru);
    hist_kernel<<<dim3(GH * 16), blk, 0, stream>>>(F, Ru, rep);
    reduce_kernel<<<dim3(16 * 16), blk, 0, stream>>>(rep, h32);
    select_kernel<<<dim3(16), blk, 0, stream>>>(h32, kptr, Ru, thr, accum, done);
    mse_kernel<<<dim3(NPAIRS * 8), dim3(512), 0, stream>>>(F, thr, accum, done, out);
}

// Round 15
// 51.855 us; speedup vs baseline: 1.3498x; 1.3476x over previous
//
#include <hip/hip_runtime.h>
#include <stdint.h>

#define N_ 2048
#define D_ 128
#define B_ 8
#define NT 16            // N_/128
#define NPAIRS 136       // NT*(NT+1)/2
#define NBINS 8192
#define GH 17            // hist block-groups per pair
#define TPG 8            // tiles per hist block (GH*TPG == NPAIRS)

typedef __attribute__((ext_vector_type(8))) _Float16 half8;
typedef __attribute__((ext_vector_type(4))) float f32x4;

// ws layout (bytes)
#define OFF_RU    256                               // 16 pairs x 16 int sub-slots
#define OFF_THR   1280                              // 16 floats
#define OFF_PART  4096                              // 64 doubles, 64B stride = 4 KB
#define OFF_H32   8192                              // 16*8192*4 = 512 KB
#define OFF_REP   (8192 + (size_t)16*NBINS*4)       // 16*17*16384 = 4.46 MB
#define OFF_F     (OFF_REP + (size_t)16*GH*(NBINS*2))
#define NEED      (OFF_F + (size_t)16*N_*D_*2)

// Fragment-major f16 panel: panel p (2048 rows x 128 k) as [128 rt][4 kt]
// 1KB fragments; within a fragment lane l=(r&15)+((k>>3)&3)*16 owns 16B at l*16.

// max over the 16 Ru sub-slots of pair p (wave-uniform scalar loads)
__device__ __forceinline__ float load_R(const int* __restrict__ Ru, int p) {
    int rb = Ru[p * 16];
    #pragma unroll
    for (int s = 1; s < 16; ++s) rb = max(rb, Ru[p * 16 + s]);
    return __int_as_float(rb);
}

// Eighth tile: fragment-row mm=0, fragment-cols nn<2 per wave ->
// rows (r mod 64)<16, cols (c mod 64)<32. 8 MFMA instead of 64. Hist sampling.
__device__ __forceinline__ void gemm16_e(const _Float16* __restrict__ Fp,
        int ti, int tj, f32x4 acc[2], int t)
{
    const int lane = t & 63;
    const int wv = t >> 6, wr = wv >> 1, wc = wv & 1;
    const _Float16* A  = Fp + (size_t)(ti*8 + wr*4)*2048 + (size_t)lane*8;
    const _Float16* Bp = Fp + (size_t)(tj*8 + wc*4)*2048 + (size_t)lane*8;

    half8 a[2], b[2][2];
    a[0] = *(const half8*)&A[0];
    #pragma unroll
    for (int nn = 0; nn < 2; ++nn) b[0][nn] = *(const half8*)&Bp[nn*2048];
    #pragma unroll
    for (int nn = 0; nn < 2; ++nn) acc[nn] = f32x4{0.f, 0.f, 0.f, 0.f};

    #pragma unroll
    for (int kt = 0; kt < 4; ++kt) {
        const int cur = kt & 1, nxt = cur ^ 1;
        if (kt < 3) {
            a[nxt] = *(const half8*)&A[(kt+1)*512];
            #pragma unroll
            for (int nn = 0; nn < 2; ++nn)
                b[nxt][nn] = *(const half8*)&Bp[nn*2048 + (kt+1)*512];
        }
        #pragma unroll
        for (int nn = 0; nn < 2; ++nn)
            acc[nn] = __builtin_amdgcn_mfma_f32_16x16x32_f16(a[cur], b[cur][nn], acc[nn], 0, 0, 0);
    }
}

// f32 -> f16 fragment-major panels + fused per-pair max row-norm^2.
// Ru: int float-bits, atomicMax into 16 sub-slots/pair (8 blocks per slot ->
// negligible same-line serialization). Poison (0xAA..) is negative -> loses.
__global__ __launch_bounds__(256) void convert_kernel(
    const float* __restrict__ Xin, const float* __restrict__ Xtg,
    _Float16* __restrict__ F, int* __restrict__ Ru)
{
    const int t = threadIdx.x;
    const int m = blockIdx.y;
    const float* X = m ? Xtg : Xin;
    const size_t e8 = (size_t)blockIdx.x * 256 + t;
    const size_t idx = e8 * 8;
    const int b = (int)(e8 >> 15);
    const int r = (int)((idx >> 7) & 2047);
    const int k = (int)(idx & 127);

    float4 v0 = *(const float4*)&X[idx];
    float4 v1 = *(const float4*)&X[idx + 4];
    float vv[8] = {v0.x, v0.y, v0.z, v0.w, v1.x, v1.y, v1.z, v1.w};
    _Float16 h8[8];
    float s = 0.f;
    #pragma unroll
    for (int j = 0; j < 8; ++j) {
        float f = fminf(fmaxf(vv[j], -60000.f), 60000.f);  // f16-range guard
        h8[j] = (_Float16)f;
        s += vv[j] * vv[j];
    }
    const int p = m * B_ + b;
    const size_t off = (size_t)p * (N_*D_)
        + (size_t)((r >> 4) * 4 + (k >> 5)) * 512
        + (size_t)((r & 15) + ((k >> 3) & 3) * 16) * 8;
    *(half8*)&F[off] = *(half8*)h8;

    // 16 consecutive lanes cover one row of 128 k
    s += __shfl_xor(s, 1); s += __shfl_xor(s, 2); s += __shfl_xor(s, 4); s += __shfl_xor(s, 8);
    s = fmaxf(s, __shfl_xor(s, 16)); s = fmaxf(s, __shfl_xor(s, 32));
    __shared__ float wm[4];
    if ((t & 63) == 0) wm[t >> 6] = s;
    __syncthreads();
    if (t == 0) {
        float mx = fmaxf(fmaxf(wm[0], wm[1]), fmaxf(wm[2], wm[3]));
        atomicMax(&Ru[p * 16 + (blockIdx.x & 15)], __float_as_int(mx));
    }
}

// Sampled (1/8) 8K-bin hist of POSITIVE sims over (0,R]: eighth-tile GEMM.
// Packed-u16 LDS, non-atomic replica flush. v<=0 skipped.
// Low 4 bits of blockIdx carry p -> pair pinned to one XCD L2.
__global__ __launch_bounds__(256) void hist_kernel(
    const _Float16* __restrict__ F, const int* __restrict__ Ru,
    uint32_t* __restrict__ rep)
{
    __shared__ uint32_t lh[NBINS / 2];   // 16 KB packed u16 pairs
    const int t = threadIdx.x;
    const int id = blockIdx.x;
    const int p = id & 15, g = id >> 4;

    for (int i = t; i < NBINS/2; i += 256) lh[i] = 0;
    __syncthreads();

    const _Float16* Fp = F + (size_t)p * (N_*D_);
    const float R = load_R(Ru, p);
    const float scl = (float)NBINS / R;

    for (int j = 0; j < TPG; ++j) {
        int rem = g * TPG + j, ti = 0;
        while (true) { int len = NT - ti; if (rem < len) break; rem -= len; ++ti; }
        const int tj = ti + rem;
        const uint32_t w = (ti == tj) ? 1u : 2u;

        f32x4 acc[2];
        gemm16_e(Fp, ti, tj, acc, t);
        #pragma unroll
        for (int nn = 0; nn < 2; ++nn)
            #pragma unroll
            for (int r = 0; r < 4; ++r) {
                float v = acc[nn][r];
                if (v > 0.f) {
                    int bin = (int)(v * scl);
                    if (bin >= NBINS) bin = NBINS - 1;
                    atomicAdd(&lh[bin >> 1], w << ((bin & 1) * 16));
                }
            }
    }
    __syncthreads();
    uint32_t* dst = rep + ((size_t)p * GH + g) * (NBINS/2);
    for (int i = t; i < NBINS/2; i += 256) dst[i] = lh[i];
}

// parallel replica reduce: 256 blocks (16 pairs x 16 chunks), coalesced.
__global__ __launch_bounds__(256) void reduce_kernel(
    const uint32_t* __restrict__ rep, uint32_t* __restrict__ h32)
{
    const int id = blockIdx.x;
    const int p = id & 15, chunk = id >> 4;
    const int t = threadIdx.x;
    const int wd = chunk * 256 + t;                 // packed-word idx 0..4095
    const uint32_t* base = rep + (size_t)p * GH * (NBINS/2) + wd;
    uint32_t lo = 0, hi = 0;
    #pragma unroll
    for (int g = 0; g < GH; ++g) {
        uint32_t x = base[(size_t)g * (NBINS/2)];
        lo += x & 0xffffu; hi += x >> 16;
    }
    uint32_t* hp = h32 + (size_t)p * NBINS;
    hp[wd*2]     = lo;
    hp[wd*2 + 1] = hi;
}

// descending scan of u32 hist, rank k/8 (1/8 sample): thr = bin lower edge.
// Block 0 also zeroes the 64 mse partial slots (stream-ordered before mse).
__global__ __launch_bounds__(256) void select_kernel(
    const uint32_t* __restrict__ h32, const int* __restrict__ kptr,
    const int* __restrict__ Ru, float* __restrict__ thr,
    double* __restrict__ part)
{
    __shared__ uint32_t csum[256], cpre[256];
    const int p = blockIdx.x, t = threadIdx.x;
    if (p == 0 && t < 64) part[t * 8] = 0.0;
    const uint32_t* h = h32 + (size_t)p * NBINS;
    const uint32_t k0 = ((uint32_t)kptr[0] + 4u) >> 3;   // sampled rank
    const float R = load_R(Ru, p);
    const float binw = R / (float)NBINS;

    const int top = NBINS - 1 - t * 32;
    uint32_t s = 0;
    #pragma unroll
    for (int j = 0; j < 32; ++j) s += h[top - j];
    csum[t] = s;
    __syncthreads();
    if (t == 0) { uint32_t run = 0; for (int i = 0; i < 256; ++i) { cpre[i] = run; run += csum[i]; } }
    __syncthreads();
    const uint32_t above = cpre[t];
    if (above < k0 && above + s >= k0) {
        uint32_t cum = above;
        for (int j = 0; j < 32; ++j) {
            int bin = top - j;
            cum += h[bin];
            if (cum >= k0) { thr[p] = (float)bin * binw; break; }   // lower edge
        }
    }
}

// masked MSE: merged dual-side GEMM pipeline (256 thr, 64x64/wave, 8 unrolled
// steps, shared operand double-buffer, dual accumulators). Per-block result
// goes to one of 64 padded partial slots -> ~17 same-line atomics instead of
// 1088 (the serialized accum chain WAS the 38µs floor). No fence, no counter.
// Low 3 bits of blockIdx carry p -> both panels (2MB) on one XCD L2.
__global__ __launch_bounds__(256) void mse_kernel(
    const _Float16* __restrict__ F, const float* __restrict__ thr,
    double* __restrict__ part)
{
    const int t = threadIdx.x;
    const int id = blockIdx.x;
    const int p = id & 7, tile = id >> 3;

    int rem = tile, ti = 0;
    while (true) { int len = NT - ti; if (rem < len) break; rem -= len; ++ti; }
    const int tj = ti + rem;
    const uint32_t w = (ti == tj) ? 1u : 2u;

    const int lane = t & 63;
    const int wv = t >> 6, wr = wv >> 1, wc = wv & 1;
    const _Float16* FI = F + (size_t)p * (N_*D_);
    const _Float16* FT = F + (size_t)(B_ + p) * (N_*D_);
    const _Float16* AI = FI + (size_t)(ti*8 + wr*4)*2048 + (size_t)lane*8;
    const _Float16* BI = FI + (size_t)(tj*8 + wc*4)*2048 + (size_t)lane*8;
    const _Float16* AT = FT + (size_t)(ti*8 + wr*4)*2048 + (size_t)lane*8;
    const _Float16* BT = FT + (size_t)(tj*8 + wc*4)*2048 + (size_t)lane*8;

    f32x4 accI[4][4], accT[4][4];
    #pragma unroll
    for (int mm = 0; mm < 4; ++mm)
        #pragma unroll
        for (int nn = 0; nn < 4; ++nn) {
            accI[mm][nn] = f32x4{0.f, 0.f, 0.f, 0.f};
            accT[mm][nn] = f32x4{0.f, 0.f, 0.f, 0.f};
        }

    half8 a[2][4], b[2][4];
    #pragma unroll
    for (int mm = 0; mm < 4; ++mm) {
        a[0][mm] = *(const half8*)&AI[mm*2048];
        b[0][mm] = *(const half8*)&BI[mm*2048];
    }

    #pragma unroll
    for (int s = 0; s < 8; ++s) {
        const int cur = s & 1, nxt = cur ^ 1;
        if (s < 7) {
            const int s2 = s + 1, kt2 = s2 & 3;
            const _Float16* A2 = (s2 < 4) ? AI : AT;
            const _Float16* B2 = (s2 < 4) ? BI : BT;
            #pragma unroll
            for (int mm = 0; mm < 4; ++mm) {
                a[nxt][mm] = *(const half8*)&A2[mm*2048 + kt2*512];
                b[nxt][mm] = *(const half8*)&B2[mm*2048 + kt2*512];
            }
        }
        if (s < 4) {
            #pragma unroll
            for (int mm = 0; mm < 4; ++mm)
                #pragma unroll
                for (int nn = 0; nn < 4; ++nn)
                    accI[mm][nn] = __builtin_amdgcn_mfma_f32_16x16x32_f16(a[cur][mm], b[cur][nn], accI[mm][nn], 0, 0, 0);
        } else {
            #pragma unroll
            for (int mm = 0; mm < 4; ++mm)
                #pragma unroll
                for (int nn = 0; nn < 4; ++nn)
                    accT[mm][nn] = __builtin_amdgcn_mfma_f32_16x16x32_f16(a[cur][mm], b[cur][nn], accT[mm][nn], 0, 0, 0);
        }
    }

    const float thrI = thr[p], thrT = thr[B_ + p];
    float local = 0.f;
    #pragma unroll
    for (int mm = 0; mm < 4; ++mm)
        #pragma unroll
        for (int nn = 0; nn < 4; ++nn)
            #pragma unroll
            for (int r = 0; r < 4; ++r) {
                float vI = accI[mm][nn][r], aI = (vI >= thrI) ? vI : 0.f;
                float vT = accT[mm][nn][r], aT = (vT >= thrT) ? vT : 0.f;
                float d = aI - aT;
                local += d * d;
            }
    local *= (float)w;
    #pragma unroll
    for (int off = 32; off; off >>= 1) local += __shfl_down(local, off);
    __shared__ float wsum[4];
    if ((t & 63) == 0) wsum[t >> 6] = local;
    __syncthreads();
    if (t == 0) {
        double s2 = (double)wsum[0] + (double)wsum[1] + (double)wsum[2] + (double)wsum[3];
        atomicAdd(&part[(id & 63) * 8], s2);
    }
}

// sum the 64 partial slots -> output scalar
__global__ void finalize_kernel(const double* __restrict__ part, float* __restrict__ out) {
    const int t = threadIdx.x;
    double s = part[t * 8];
    #pragma unroll
    for (int off = 32; off; off >>= 1) s += __shfl_down(s, off);
    if (t == 0) out[0] = (float)(s / ((double)B_ * (double)N_ * (double)N_));
}

extern "C" void kernel_launch(void* const* d_in, const int* in_sizes, int n_in,
                              void* d_out, int out_size, void* d_ws, size_t ws_size,
                              hipStream_t stream)
{
    const float* Xin = (const float*)d_in[0];
    const float* Xtg = (const float*)d_in[1];
    const int*  kptr = (const int*)d_in[3];
    float* out = (float*)d_out;

    char* ws = (char*)d_ws;
    int*       Ru    = (int*)      (ws + OFF_RU);
    float*     thr   = (float*)    (ws + OFF_THR);
    double*    part  = (double*)   (ws + OFF_PART);
    uint32_t*  h32   = (uint32_t*) (ws + OFF_H32);
    uint32_t*  rep   = (uint32_t*) (ws + OFF_REP);
    _Float16*  F     = (_Float16*) (ws + OFF_F);
    if (ws_size < NEED) return;

    dim3 blk(256);
    convert_kernel<<<dim3(1024, 2), blk, 0, stream>>>(Xin, Xtg, F, Ru);
    hist_kernel<<<dim3(GH * 16), blk, 0, stream>>>(F, Ru, rep);
    reduce_kernel<<<dim3(16 * 16), blk, 0, stream>>>(rep, h32);
    select_kernel<<<dim3(16), blk, 0, stream>>>(h32, kptr, Ru, thr, part);
    mse_kernel<<<dim3(NPAIRS * 8), blk, 0, stream>>>(F, thr, part);
    finalize_kernel<<<1, 64, 0, stream>>>(part, out);
}